// Round 13
// baseline (54.177 us; speedup 1.0000x reference)
//
#include <hip/hip_runtime.h>

// PairwiseRankLoss: U=262144 users x G=64 items, K=2, MARGIN=0.3
// 4 users/wave group of 16 lanes, 4 items/lane. R13:
//  R12 compute (GF(2)^3-remapped all-DPP bitonic, signed-space dirs,
//  index-embedded selection keys, LDS y_hat gather) restructured as
//  DUAL-CHAIN: two bodies (8 users) per chunk, textually interleaved so
//  the scheduler co-issues two independent dependency chains per wave.
//  (R6-R12 invariant: VALUBusy ~45% == ONE chain's duty cycle; waves are
//  phase-locked so TLP never covered the chain stalls. ILP must come from
//  within the wave. R7's dual-chain failed on global-load sinking; with
//  LDS staging the chain sources are ds_reads the compiler schedules.)
//  Staging: 2 slots x 2-body chunks via global_load_lds, stage(c+2) after
//  consuming c, counted s_waitcnt vmcnt(6), per-wave, no barriers.
// Deterministic two-stage reduction via d_ws.

static constexpr int kUsers = 262144;
static constexpr int kBlock = 256;                  // 4 waves / block
static constexpr int kGrid  = 2048;
static constexpr int kWavesPerBlock = kBlock / 64;
static constexpr int kTotalWaves = kGrid * kWavesPerBlock;   // 8192
static constexpr int kUsersPerWave = kUsers / kTotalWaves;   // 32
static constexpr int kChunks = 4;                   // 2 bodies (8 users) each
static constexpr float kMargin = 0.3f;

template<int CTRL>
static __device__ __forceinline__ float movdppf(float x) {
    return __uint_as_float((unsigned)__builtin_amdgcn_mov_dpp(
        (int)__float_as_uint(x), CTRL, 0xF, 0xF, false));
}
template<int CTRL>
static __device__ __forceinline__ unsigned movdppu(unsigned x) {
    return (unsigned)__builtin_amdgcn_mov_dpp((int)x, CTRL, 0xF, 0xF, false);
}
static __device__ __forceinline__ float xorf(float x, unsigned m) {
    return __uint_as_float(__float_as_uint(x) ^ m);
}
static __device__ __forceinline__ float cnd(float mx, float mn,
                                            unsigned long long keep) {
    float d;
    asm("v_cndmask_b32 %0, %1, %2, %3" : "=v"(d) : "v"(mx), "v"(mn), "s"(keep));
    return d;
}
template<int CTRL>
static __device__ __forceinline__ float cexd(float w, unsigned long long keep) {
    const float p = movdppf<CTRL>(w);
    return cnd(fmaxf(w, p), fminf(w, p), keep);
}
static __device__ __forceinline__ unsigned umax_(unsigned a, unsigned b){ return a>b?a:b; }
static __device__ __forceinline__ unsigned umin_(unsigned a, unsigned b){ return a<b?a:b; }

// async global -> LDS, 16B/lane; LDS dest = uniform base + lane*16
static __device__ __forceinline__ void gl_lds16(const float* g, float* l) {
    __builtin_amdgcn_global_load_lds(
        (const __attribute__((address_space(1))) void*)g,
        (__attribute__((address_space(3))) void*)l, 16, 0, 0);
}

#define CE2A(a, b) { float mn_=fminf(a,b), mx_=fmaxf(a,b); (a)=mn_; (b)=mx_; }
#define CE2D(a, b) { float mn_=fminf(a,b), mx_=fmaxf(a,b); (a)=mx_; (b)=mn_; }
// dual-body variants: every line touches both chains (adjacent indep ops)
#define FLIP8(m)   { a0=xorf(a0,m); b0=xorf(b0,m); a1=xorf(a1,m); b1=xorf(b1,m); \
                     a2=xorf(a2,m); b2=xorf(b2,m); a3=xorf(a3,m); b3=xorf(b3,m); }
#define CEX8(CTRL, keep) { a0=cexd<CTRL>(a0,keep); b0=cexd<CTRL>(b0,keep); \
                           a1=cexd<CTRL>(a1,keep); b1=cexd<CTRL>(b1,keep); \
                           a2=cexd<CTRL>(a2,keep); b2=cexd<CTRL>(b2,keep); \
                           a3=cexd<CTRL>(a3,keep); b3=cexd<CTRL>(b3,keep); }
#define INL8_J2    { CE2A(a0,a2); CE2A(b0,b2); CE2A(a1,a3); CE2A(b1,b3); }
#define INL8_J1    { CE2A(a0,a1); CE2A(b0,b1); CE2A(a2,a3); CE2A(b2,b3); }
#define FOLD2(m1, m2, CTRL) { \
    unsigned q1_ = movdppu<CTRL>(m1), q2_ = movdppu<CTRL>(m2); \
    unsigned lo_ = umin_(m1, q1_); \
    m1 = umax_(m1, q1_); \
    m2 = umax_(lo_, umax_(m2, q2_)); }

__global__ __launch_bounds__(kBlock, 3)
void prl_user_kernel(const float* __restrict__ y_hat,
                     const float* __restrict__ y_true,
                     const float* __restrict__ rnd,
                     float* __restrict__ partials)
{
    const int lane = threadIdx.x & 63;
    const int wv   = threadIdx.x >> 6;
    const int wid  = (blockIdx.x * kBlock + threadIdx.x) >> 6;
    const int t    = lane & 15;          // lane within user group
    const int g    = lane >> 4;          // user group (0..3) within wave

    // logical coords: tt = M^-1(physical t) for map {1,2,4}->{1,2,7}
    const int p2   = (t >> 2) & 1;
    const int tt0  = (t & 1) ^ p2;
    const int tt1  = ((t >> 1) & 1) ^ p2;
    const int tt2  = p2;
    const int half = (t >> 3) & 1;

    const unsigned SGN = 0x80000000u;
    const unsigned flipA = tt0 ? SGN : 0u;
    const unsigned flipB = (tt0 ^ tt1) ? SGN : 0u;
    const unsigned flipC = (tt1 ^ tt2) ? SGN : 0u;
    const unsigned flipD = (tt2 ^ half) ? SGN : 0u;   // + B-half descending
    const unsigned sgnB  = half ? SGN : 0u;
    const unsigned long long keep1 = __ballot(tt0 == 0);
    const unsigned long long keep2 = __ballot(tt1 == 0);
    const unsigned long long keep4 = __ballot(tt2 == 0);

    const unsigned cb = 63u - ((unsigned)t << 2);   // 63 - item_idx base

    // [wave][slot 0..1][body 0..1][array(yt,r,yh)][256 floats] = 48 KB/block
    __shared__ __align__(16) float sbuf[kWavesPerBlock][2][2][3][256];
    __shared__ float wsum[kWavesPerBlock];

    const int ub = wid * kUsersPerWave;
    auto stage = [&](int slot, int chunk) {
        #pragma unroll
        for (int body = 0; body < 2; ++body) {
            const int gi = ((ub + (chunk * 2 + body) * 4) << 6) + (lane << 2);
            float* dst = &sbuf[wv][slot][body][0][0];
            gl_lds16(y_true + gi, dst);
            gl_lds16(rnd   + gi, dst + 256);
            gl_lds16(y_hat + gi, dst + 512);
        }
    };

    stage(0, 0);
    stage(1, 1);

    float acc = 0.0f;
    #pragma unroll 1
    for (int c = 0; c < kChunks; ++c) {
        if (c < kChunks - 1) {
            asm volatile("s_waitcnt vmcnt(6)" ::: "memory");   // chunk c ready
        } else {
            asm volatile("s_waitcnt vmcnt(0)" ::: "memory");
        }
        const int slot = c & 1;
        const float* bufA = &sbuf[wv][slot][0][0][0];
        const float* bufB = &sbuf[wv][slot][1][0][0];
        const float4 vtA = *reinterpret_cast<const float4*>(bufA + (lane << 2));
        const float4 vtB = *reinterpret_cast<const float4*>(bufB + (lane << 2));
        const float4 vrA = *reinterpret_cast<const float4*>(bufA + 256 + (lane << 2));
        const float4 vrB = *reinterpret_cast<const float4*>(bufB + 256 + (lane << 2));
        const float* yhA = bufA + 512 + (g << 6);
        const float* yhB = bufB + 512 + (g << 6);

        // ---- dual signed-space bitonic (A,B interleaved) ----
        float a0 = vtA.x, a1 = vtA.y, a2 = vtA.z, a3 = vtA.w;
        float b0 = vtB.x, b1 = vtB.y, b2 = vtB.z, b3 = vtB.w;
        CE2A(a0, a1); CE2A(b0, b1); CE2D(a2, a3); CE2D(b2, b3);   // k=2
        FLIP8(flipA);
        INL8_J2; INL8_J1;                                         // k=4
        FLIP8(flipB);
        CEX8(0xB1, keep1);                                        // k=8 j=4
        INL8_J2; INL8_J1;
        FLIP8(flipC);
        CEX8(0x4E, keep2);                                        // k=16 j=8
        CEX8(0xB1, keep1);
        INL8_J2; INL8_J1;
        FLIP8(flipD);
        CEX8(0x141, keep4);                                       // k=32 j=16
        CEX8(0x4E, keep2);
        CEX8(0xB1, keep1);
        INL8_J2; INL8_J1;

        // unflip B-half sign; split = min with ror8 partner
        FLIP8(sgnB);
        const float lA0 = fminf(a0, movdppf<0x128>(a0));
        const float lB0 = fminf(b0, movdppf<0x128>(b0));
        const float lA1 = fminf(a1, movdppf<0x128>(a1));
        const float lB1 = fminf(b1, movdppf<0x128>(b1));
        const float lA2 = fminf(a2, movdppf<0x128>(a2));
        const float lB2 = fminf(b2, movdppf<0x128>(b2));
        const float lA3 = fminf(a3, movdppf<0x128>(a3));
        const float lB3 = fminf(b3, movdppf<0x128>(b3));

        float mA = fmaxf(fmaxf(lA0, lA1), fmaxf(lA2, lA3));
        float mB = fmaxf(fmaxf(lB0, lB1), fmaxf(lB2, lB3));
        mA = fmaxf(mA, movdppf<0x124>(mA)); mB = fmaxf(mB, movdppf<0x124>(mB));
        mA = fmaxf(mA, movdppf<0x122>(mA)); mB = fmaxf(mB, movdppf<0x122>(mB));
        mA = fmaxf(mA, movdppf<0x121>(mA)); mB = fmaxf(mB, movdppf<0x121>(mB));
        const float a31A = mA, a31B = mB;              // group-uniform

        // ---- selection keys: (r & ~63) | (63 - item_idx) ----
        const bool pA0 = vtA.x > a31A, pA1 = vtA.y > a31A,
                   pA2 = vtA.z > a31A, pA3 = vtA.w > a31A;
        const bool pB0 = vtB.x > a31B, pB1 = vtB.y > a31B,
                   pB2 = vtB.z > a31B, pB3 = vtB.w > a31B;
        const unsigned kA0 = (__float_as_uint(vrA.x) & ~63u) | cb;
        const unsigned kA1 = (__float_as_uint(vrA.y) & ~63u) | (cb - 1u);
        const unsigned kA2 = (__float_as_uint(vrA.z) & ~63u) | (cb - 2u);
        const unsigned kA3 = (__float_as_uint(vrA.w) & ~63u) | (cb - 3u);
        const unsigned kB0 = (__float_as_uint(vrB.x) & ~63u) | cb;
        const unsigned kB1 = (__float_as_uint(vrB.y) & ~63u) | (cb - 1u);
        const unsigned kB2 = (__float_as_uint(vrB.z) & ~63u) | (cb - 2u);
        const unsigned kB3 = (__float_as_uint(vrB.w) & ~63u) | (cb - 3u);

        auto top2 = [&](unsigned k0, unsigned k1, unsigned k2, unsigned k3,
                        unsigned& m1, unsigned& m2) {
            const unsigned x1 = umax_(k0,k1), x2 = umin_(k0,k1);
            const unsigned y1 = umax_(k2,k3), y2 = umin_(k2,k3);
            m1 = umax_(x1,y1);
            m2 = umax_(umin_(x1,y1), umax_(x2,y2));
            FOLD2(m1, m2, 0x128);
            FOLD2(m1, m2, 0x124);
            FOLD2(m1, m2, 0x122);
            FOLD2(m1, m2, 0x121);
        };
        unsigned pmA1, pmA2, nmA1, nmA2, pmB1, pmB2, nmB1, nmB2;
        top2(pA0 ? kA0 : 0u, pA1 ? kA1 : 0u, pA2 ? kA2 : 0u, pA3 ? kA3 : 0u, pmA1, pmA2);
        top2(pB0 ? kB0 : 0u, pB1 ? kB1 : 0u, pB2 ? kB2 : 0u, pB3 ? kB3 : 0u, pmB1, pmB2);
        top2(pA0 ? 0u : kA0, pA1 ? 0u : kA1, pA2 ? 0u : kA2, pA3 ? 0u : kA3, nmA1, nmA2);
        top2(pB0 ? 0u : kB0, pB1 ? 0u : kB1, pB2 ? 0u : kB2, pB3 ? 0u : kB3, nmB1, nmB2);

        // winner gather from staged y_hat rows (uniform broadcast reads)
        const float PA0 = yhA[(pmA1 & 63u) ^ 63u];
        const float PB0 = yhB[(pmB1 & 63u) ^ 63u];
        const float PA1 = yhA[(pmA2 & 63u) ^ 63u];
        const float PB1 = yhB[(pmB2 & 63u) ^ 63u];
        const float NA0 = yhA[(nmA1 & 63u) ^ 63u];
        const float NB0 = yhB[(nmB1 & 63u) ^ 63u];
        const float NA1 = yhA[(nmA2 & 63u) ^ 63u];
        const float NB1 = yhB[(nmB2 & 63u) ^ 63u];

        float sA = 0.0f, sB = 0.0f;
        sA += fmaxf(kMargin - (PA0 - NA0), 0.0f);
        sB += fmaxf(kMargin - (PB0 - NB0), 0.0f);
        sA += fmaxf(kMargin - (PA0 - NA1), 0.0f);
        sB += fmaxf(kMargin - (PB0 - NB1), 0.0f);
        sA += fmaxf(kMargin - (PA1 - NA0), 0.0f);
        sB += fmaxf(kMargin - (PB1 - NB0), 0.0f);
        sA += fmaxf(kMargin - (PA1 - NA1), 0.0f);
        sB += fmaxf(kMargin - (PB1 - NB1), 0.0f);
        acc = fmaf(0.25f, sA + sB, acc);

        if (c + 2 < kChunks) stage(slot, c + 2);    // overwrite consumed slot
    }

    // acc uniform within each 16-lane group; sum the 4 group leaders
    float contrib = (t == 0) ? acc : 0.0f;
    contrib += __shfl_xor(contrib, 32);
    contrib += __shfl_xor(contrib, 16);

    if (lane == 0) wsum[wv] = contrib;
    __syncthreads();
    if (threadIdx.x == 0) {
        float tsum = 0.0f;
        #pragma unroll
        for (int i = 0; i < kWavesPerBlock; ++i) tsum += wsum[i];
        partials[blockIdx.x] = tsum;
    }
}

__global__ void prl_reduce_kernel(const float* __restrict__ partials,
                                  float* __restrict__ out)
{
    float tv = 0.0f;
    for (int i = threadIdx.x; i < kGrid; i += 256) tv += partials[i];
    #pragma unroll
    for (int s = 32; s > 0; s >>= 1) tv += __shfl_xor(tv, s);
    __shared__ float ws[4];
    if ((threadIdx.x & 63) == 0) ws[threadIdx.x >> 6] = tv;
    __syncthreads();
    if (threadIdx.x == 0) {
        out[0] = (ws[0] + ws[1] + ws[2] + ws[3]) * (1.0f / (float)kUsers);
    }
}

extern "C" void kernel_launch(void* const* d_in, const int* in_sizes, int n_in,
                              void* d_out, int out_size, void* d_ws, size_t ws_size,
                              hipStream_t stream) {
    const float* y_hat  = (const float*)d_in[0];
    const float* y_true = (const float*)d_in[1];
    const float* rnd    = (const float*)d_in[2];
    // d_in[3] = user_idx: contiguous equal-size segments -> never read
    float* partials = (float*)d_ws;          // kGrid floats = 8 KiB scratch
    float* out      = (float*)d_out;

    hipLaunchKernelGGL(prl_user_kernel, dim3(kGrid), dim3(kBlock), 0, stream,
                       y_hat, y_true, rnd, partials);
    hipLaunchKernelGGL(prl_reduce_kernel, dim3(1), dim3(256), 0, stream,
                       partials, out);
}

// Round 14
// 45.949 us; speedup vs baseline: 1.1791x; 1.1791x over previous
//
#include <hip/hip_runtime.h>

// PairwiseRankLoss: U=262144 users x G=64 items, K=2, MARGIN=0.3
// 4 users/wave group of 16 lanes, 4 items/lane. R14 = best-of-R9+R13:
//  - R13 dual-chain compute: two 4-user bodies textually interleaved
//    (proven +26% per-wave issue efficiency, VGPR 68)
//  - R9 memory path: direct global float4 loads (no staging machinery --
//    R9 at 48.0us beat all staged variants), small LDS y_hat gather table
//  - launch_bounds(256,6): cap VGPR at 84, keep 24 waves/CU (R13's LB3
//    crashed occupancy to 26% and forfeited the ILP gain)
// Compute: GF(2)^3-remapped all-DPP signed-space bitonic, split vs ror8,
// a31 = max(lower32); index-embedded selection keys; LDS uniform gather.
// Deterministic two-stage reduction via d_ws.

static constexpr int kUsers = 262144;
static constexpr int kBlock = 256;                  // 4 waves / block
static constexpr int kGrid  = 2048;
static constexpr int kWavesPerBlock = kBlock / 64;
static constexpr int kTotalWaves = kGrid * kWavesPerBlock;   // 8192
static constexpr int kUsersPerWave = kUsers / kTotalWaves;   // 32
static constexpr int kChunks = 4;                   // 2 bodies (8 users) each
static constexpr float kMargin = 0.3f;

template<int CTRL>
static __device__ __forceinline__ float movdppf(float x) {
    return __uint_as_float((unsigned)__builtin_amdgcn_mov_dpp(
        (int)__float_as_uint(x), CTRL, 0xF, 0xF, false));
}
template<int CTRL>
static __device__ __forceinline__ unsigned movdppu(unsigned x) {
    return (unsigned)__builtin_amdgcn_mov_dpp((int)x, CTRL, 0xF, 0xF, false);
}
static __device__ __forceinline__ float xorf(float x, unsigned m) {
    return __uint_as_float(__float_as_uint(x) ^ m);
}
static __device__ __forceinline__ float cnd(float mx, float mn,
                                            unsigned long long keep) {
    float d;
    asm("v_cndmask_b32 %0, %1, %2, %3" : "=v"(d) : "v"(mx), "v"(mn), "s"(keep));
    return d;
}
template<int CTRL>
static __device__ __forceinline__ float cexd(float w, unsigned long long keep) {
    const float p = movdppf<CTRL>(w);
    return cnd(fmaxf(w, p), fminf(w, p), keep);
}
static __device__ __forceinline__ unsigned umax_(unsigned a, unsigned b){ return a>b?a:b; }
static __device__ __forceinline__ unsigned umin_(unsigned a, unsigned b){ return a<b?a:b; }

#define CE2A(a, b) { float mn_=fminf(a,b), mx_=fmaxf(a,b); (a)=mn_; (b)=mx_; }
#define CE2D(a, b) { float mn_=fminf(a,b), mx_=fmaxf(a,b); (a)=mx_; (b)=mn_; }
// dual-body macros: every line touches both chains (adjacent indep ops)
#define FLIP8(m)   { a0=xorf(a0,m); b0=xorf(b0,m); a1=xorf(a1,m); b1=xorf(b1,m); \
                     a2=xorf(a2,m); b2=xorf(b2,m); a3=xorf(a3,m); b3=xorf(b3,m); }
#define CEX8(CTRL, keep) { a0=cexd<CTRL>(a0,keep); b0=cexd<CTRL>(b0,keep); \
                           a1=cexd<CTRL>(a1,keep); b1=cexd<CTRL>(b1,keep); \
                           a2=cexd<CTRL>(a2,keep); b2=cexd<CTRL>(b2,keep); \
                           a3=cexd<CTRL>(a3,keep); b3=cexd<CTRL>(b3,keep); }
#define INL8_J2    { CE2A(a0,a2); CE2A(b0,b2); CE2A(a1,a3); CE2A(b1,b3); }
#define INL8_J1    { CE2A(a0,a1); CE2A(b0,b1); CE2A(a2,a3); CE2A(b2,b3); }
#define FOLD2(m1, m2, CTRL) { \
    unsigned q1_ = movdppu<CTRL>(m1), q2_ = movdppu<CTRL>(m2); \
    unsigned lo_ = umin_(m1, q1_); \
    m1 = umax_(m1, q1_); \
    m2 = umax_(lo_, umax_(m2, q2_)); }

__global__ __launch_bounds__(kBlock, 6)
void prl_user_kernel(const float* __restrict__ y_hat,
                     const float* __restrict__ y_true,
                     const float* __restrict__ rnd,
                     float* __restrict__ partials)
{
    const int lane = threadIdx.x & 63;
    const int wv   = threadIdx.x >> 6;
    const int wid  = (blockIdx.x * kBlock + threadIdx.x) >> 6;
    const int t    = lane & 15;          // lane within user group
    const int g    = lane >> 4;          // user group (0..3) within wave

    // logical coords: tt = M^-1(physical t) for map {1,2,4}->{1,2,7}
    const int p2   = (t >> 2) & 1;
    const int tt0  = (t & 1) ^ p2;
    const int tt1  = ((t >> 1) & 1) ^ p2;
    const int tt2  = p2;
    const int half = (t >> 3) & 1;

    const unsigned SGN = 0x80000000u;
    const unsigned flipA = tt0 ? SGN : 0u;
    const unsigned flipB = (tt0 ^ tt1) ? SGN : 0u;
    const unsigned flipC = (tt1 ^ tt2) ? SGN : 0u;
    const unsigned flipD = (tt2 ^ half) ? SGN : 0u;   // + B-half descending
    const unsigned sgnB  = half ? SGN : 0u;
    const unsigned long long keep1 = __ballot(tt0 == 0);
    const unsigned long long keep2 = __ballot(tt1 == 0);
    const unsigned long long keep4 = __ballot(tt2 == 0);

    const unsigned cb = 63u - ((unsigned)t << 2);   // 63 - item_idx base

    // y_hat gather tables: [wave][body][group][64] = 8 KB/block
    __shared__ __align__(16) float yh_tab[kWavesPerBlock][2][4][64];
    __shared__ float wsum[kWavesPerBlock];

    const int ub = wid * kUsersPerWave;

    float acc = 0.0f;
    #pragma unroll 1
    for (int c = 0; c < kChunks; ++c) {
        const int idxA = ((ub + c * 8) << 6) + (lane << 2);
        const int idxB = idxA + 256;
        const float4 vtA = *reinterpret_cast<const float4*>(y_true + idxA);
        const float4 vtB = *reinterpret_cast<const float4*>(y_true + idxB);
        const float4 vrA = *reinterpret_cast<const float4*>(rnd   + idxA);
        const float4 vrB = *reinterpret_cast<const float4*>(rnd   + idxB);
        const float4 vhA = *reinterpret_cast<const float4*>(y_hat + idxA);
        const float4 vhB = *reinterpret_cast<const float4*>(y_hat + idxB);

        float* tabA = &yh_tab[wv][0][g][0];
        float* tabB = &yh_tab[wv][1][g][0];
        *reinterpret_cast<float4*>(tabA + (t << 2)) = vhA;
        *reinterpret_cast<float4*>(tabB + (t << 2)) = vhB;

        // ---- dual signed-space bitonic (A,B interleaved) ----
        float a0 = vtA.x, a1 = vtA.y, a2 = vtA.z, a3 = vtA.w;
        float b0 = vtB.x, b1 = vtB.y, b2 = vtB.z, b3 = vtB.w;
        CE2A(a0, a1); CE2A(b0, b1); CE2D(a2, a3); CE2D(b2, b3);   // k=2
        FLIP8(flipA);
        INL8_J2; INL8_J1;                                         // k=4
        FLIP8(flipB);
        CEX8(0xB1, keep1);                                        // k=8 j=4
        INL8_J2; INL8_J1;
        FLIP8(flipC);
        CEX8(0x4E, keep2);                                        // k=16 j=8
        CEX8(0xB1, keep1);
        INL8_J2; INL8_J1;
        FLIP8(flipD);
        CEX8(0x141, keep4);                                       // k=32 j=16
        CEX8(0x4E, keep2);
        CEX8(0xB1, keep1);
        INL8_J2; INL8_J1;

        // unflip B-half sign; split = min with ror8 partner
        FLIP8(sgnB);
        const float lA0 = fminf(a0, movdppf<0x128>(a0));
        const float lB0 = fminf(b0, movdppf<0x128>(b0));
        const float lA1 = fminf(a1, movdppf<0x128>(a1));
        const float lB1 = fminf(b1, movdppf<0x128>(b1));
        const float lA2 = fminf(a2, movdppf<0x128>(a2));
        const float lB2 = fminf(b2, movdppf<0x128>(b2));
        const float lA3 = fminf(a3, movdppf<0x128>(a3));
        const float lB3 = fminf(b3, movdppf<0x128>(b3));

        float mA = fmaxf(fmaxf(lA0, lA1), fmaxf(lA2, lA3));
        float mB = fmaxf(fmaxf(lB0, lB1), fmaxf(lB2, lB3));
        mA = fmaxf(mA, movdppf<0x124>(mA)); mB = fmaxf(mB, movdppf<0x124>(mB));
        mA = fmaxf(mA, movdppf<0x122>(mA)); mB = fmaxf(mB, movdppf<0x122>(mB));
        mA = fmaxf(mA, movdppf<0x121>(mA)); mB = fmaxf(mB, movdppf<0x121>(mB));
        const float a31A = mA, a31B = mB;              // group-uniform

        // ---- selection keys: (r & ~63) | (63 - item_idx) ----
        const bool pA0 = vtA.x > a31A, pA1 = vtA.y > a31A,
                   pA2 = vtA.z > a31A, pA3 = vtA.w > a31A;
        const bool pB0 = vtB.x > a31B, pB1 = vtB.y > a31B,
                   pB2 = vtB.z > a31B, pB3 = vtB.w > a31B;
        const unsigned kA0 = (__float_as_uint(vrA.x) & ~63u) | cb;
        const unsigned kA1 = (__float_as_uint(vrA.y) & ~63u) | (cb - 1u);
        const unsigned kA2 = (__float_as_uint(vrA.z) & ~63u) | (cb - 2u);
        const unsigned kA3 = (__float_as_uint(vrA.w) & ~63u) | (cb - 3u);
        const unsigned kB0 = (__float_as_uint(vrB.x) & ~63u) | cb;
        const unsigned kB1 = (__float_as_uint(vrB.y) & ~63u) | (cb - 1u);
        const unsigned kB2 = (__float_as_uint(vrB.z) & ~63u) | (cb - 2u);
        const unsigned kB3 = (__float_as_uint(vrB.w) & ~63u) | (cb - 3u);

        auto top2 = [&](unsigned k0, unsigned k1, unsigned k2, unsigned k3,
                        unsigned& m1, unsigned& m2) {
            const unsigned x1 = umax_(k0,k1), x2 = umin_(k0,k1);
            const unsigned y1 = umax_(k2,k3), y2 = umin_(k2,k3);
            m1 = umax_(x1,y1);
            m2 = umax_(umin_(x1,y1), umax_(x2,y2));
            FOLD2(m1, m2, 0x128);
            FOLD2(m1, m2, 0x124);
            FOLD2(m1, m2, 0x122);
            FOLD2(m1, m2, 0x121);
        };
        unsigned pmA1, pmA2, nmA1, nmA2, pmB1, pmB2, nmB1, nmB2;
        top2(pA0 ? kA0 : 0u, pA1 ? kA1 : 0u, pA2 ? kA2 : 0u, pA3 ? kA3 : 0u, pmA1, pmA2);
        top2(pB0 ? kB0 : 0u, pB1 ? kB1 : 0u, pB2 ? kB2 : 0u, pB3 ? kB3 : 0u, pmB1, pmB2);
        top2(pA0 ? 0u : kA0, pA1 ? 0u : kA1, pA2 ? 0u : kA2, pA3 ? 0u : kA3, nmA1, nmA2);
        top2(pB0 ? 0u : kB0, pB1 ? 0u : kB1, pB2 ? 0u : kB2, pB3 ? 0u : kB3, nmB1, nmB2);

        // winner gather from LDS tables (uniform broadcast reads)
        const float PA0 = tabA[(pmA1 & 63u) ^ 63u];
        const float PB0 = tabB[(pmB1 & 63u) ^ 63u];
        const float PA1 = tabA[(pmA2 & 63u) ^ 63u];
        const float PB1 = tabB[(pmB2 & 63u) ^ 63u];
        const float NA0 = tabA[(nmA1 & 63u) ^ 63u];
        const float NB0 = tabB[(nmB1 & 63u) ^ 63u];
        const float NA1 = tabA[(nmA2 & 63u) ^ 63u];
        const float NB1 = tabB[(nmB2 & 63u) ^ 63u];

        float sA = 0.0f, sB = 0.0f;
        sA += fmaxf(kMargin - (PA0 - NA0), 0.0f);
        sB += fmaxf(kMargin - (PB0 - NB0), 0.0f);
        sA += fmaxf(kMargin - (PA0 - NA1), 0.0f);
        sB += fmaxf(kMargin - (PB0 - NB1), 0.0f);
        sA += fmaxf(kMargin - (PA1 - NA0), 0.0f);
        sB += fmaxf(kMargin - (PB1 - NB0), 0.0f);
        sA += fmaxf(kMargin - (PA1 - NA1), 0.0f);
        sB += fmaxf(kMargin - (PB1 - NB1), 0.0f);
        acc = fmaf(0.25f, sA + sB, acc);
    }

    // acc uniform within each 16-lane group; sum the 4 group leaders
    float contrib = (t == 0) ? acc : 0.0f;
    contrib += __shfl_xor(contrib, 32);
    contrib += __shfl_xor(contrib, 16);

    if (lane == 0) wsum[wv] = contrib;
    __syncthreads();
    if (threadIdx.x == 0) {
        float tsum = 0.0f;
        #pragma unroll
        for (int i = 0; i < kWavesPerBlock; ++i) tsum += wsum[i];
        partials[blockIdx.x] = tsum;
    }
}

__global__ void prl_reduce_kernel(const float* __restrict__ partials,
                                  float* __restrict__ out)
{
    float tv = 0.0f;
    for (int i = threadIdx.x; i < kGrid; i += 256) tv += partials[i];
    #pragma unroll
    for (int s = 32; s > 0; s >>= 1) tv += __shfl_xor(tv, s);
    __shared__ float ws[4];
    if ((threadIdx.x & 63) == 0) ws[threadIdx.x >> 6] = tv;
    __syncthreads();
    if (threadIdx.x == 0) {
        out[0] = (ws[0] + ws[1] + ws[2] + ws[3]) * (1.0f / (float)kUsers);
    }
}

extern "C" void kernel_launch(void* const* d_in, const int* in_sizes, int n_in,
                              void* d_out, int out_size, void* d_ws, size_t ws_size,
                              hipStream_t stream) {
    const float* y_hat  = (const float*)d_in[0];
    const float* y_true = (const float*)d_in[1];
    const float* rnd    = (const float*)d_in[2];
    // d_in[3] = user_idx: contiguous equal-size segments -> never read
    float* partials = (float*)d_ws;          // kGrid floats = 8 KiB scratch
    float* out      = (float*)d_out;

    hipLaunchKernelGGL(prl_user_kernel, dim3(kGrid), dim3(kBlock), 0, stream,
                       y_hat, y_true, rnd, partials);
    hipLaunchKernelGGL(prl_reduce_kernel, dim3(1), dim3(256), 0, stream,
                       partials, out);
}